// Round 2
// baseline (136.610 us; speedup 1.0000x reference)
//
#include <hip/hip_runtime.h>

#define HW 256
#define CH 64
#define NPIX (4 * HW * HW)          // 262144 pixels
#define WS_BYTES ((size_t)NPIX * 24) // 12 u16 per pixel (9 used, 3 pad)

// ===================== Kernel A: address precompute =====================
// One thread per (pixel, tap). Computes the deformed nearest-floor sample
// coordinate (reference semantics) and stores (y0<<8)|x0 as u16.
// off read is perfectly coalesced: thread g reads float2 at byte g*8.
__global__ __launch_bounds__(256, 8) void DeformA_kernel(
    const float* __restrict__ gt,     // [256,256]
    const float* __restrict__ off,    // [4,256,256,18]
    unsigned short* __restrict__ ws)  // [NPIX][12]
{
    const unsigned g = blockIdx.x * 256u + threadIdx.x;   // < NPIX*9
    const unsigned p = g / 9u;                             // magic-mul, no div
    const int tap = (int)(g - p * 9u);
    const int i = (int)((p >> 8) & 255u);
    const int j = (int)(p & 255u);
    const int ky = tap / 3, kx = tap - ky * 3;

    // chain head: issue immediately
    const float2 o2 = *(const float2*)(off + (size_t)g * 2);

    const int iy = i + ky - 1, ix = j + kx - 1;
    const bool interior = (iy >= 0) & (iy < HW) & (ix >= 0) & (ix < HW);
    const int yi = interior ? iy : 0;
    const int xi = interior ? ix : 0;
    // base-mask load issues while o2 is in flight
    const float p_mask = (yi >= 1 && xi >= 1) ? gt[(yi - 1) * HW + (xi - 1)] : 0.f;

    const float yf = (float)yi, xf = (float)xi;
    const float yof = fminf(fmaxf(floorf(yf + o2.x), 0.f), 257.f);
    const float xof = fminf(fmaxf(floorf(xf + o2.y), 0.f), 257.f);
    const int yo = (int)yof, xo = (int)xof;
    const float p_mask_off = (yo >= 1 && yo <= HW && xo >= 1 && xo <= HW)
                             ? gt[(yo - 1) * HW + (xo - 1)] : 0.f;
    const float diff = (p_mask != p_mask_off) ? 1.f : 0.f;
    const float y = fminf(fmaxf(yf + o2.x * diff, 0.f), 255.f);
    const float x = fminf(fmaxf(xf + o2.y * diff, 0.f), 255.f);
    const int y0 = (int)y, x0 = (int)x;   // both in [0,255]; valid iff >=1

    ws[p * 12u + (unsigned)tap] = (unsigned short)((y0 << 8) | x0);
}

// ===================== Kernel B: gather + FMA =====================
// 256 threads = 4 waves, 4 px/wave, 16 lanes/px (lane%16 = channel quad).
// Encoded coords arrive via 3 group-uniform 8B/4B loads (HW broadcast),
// decode is pure VALU, then ALL 9 gathers issue as one batch.
// __launch_bounds__(256,4): VGPR cap 128 so the allocator cannot chunk
// the 36-reg gather batch (round-1 lesson: at cap 64 it serialized).
__global__ __launch_bounds__(256, 4) void DeformB_kernel(
    const float* __restrict__ inp,    // [4,256,256,64]
    const unsigned short* __restrict__ ws,
    const float* __restrict__ ker,    // [9][64]
    const float* __restrict__ bias,   // [1]
    float* __restrict__ out)          // [4,256,256]
{
    __shared__ float wlds[576];       // 9 taps x 64 ch
    const int tid = threadIdx.x;
    if (tid < 144) ((float4*)wlds)[tid] = ((const float4*)ker)[tid];

    const int lane = tid & 63;
    const int wave = tid >> 6;
    const int t = lane & 15;

    // XCD swizzle: contiguous 2048-block chunk per XCD (16384 blocks)
    const int bid = blockIdx.x;
    const int vb = (bid & 7) * 2048 + (bid >> 3);
    const int p = vb * 16 + wave * 4 + (lane >> 4);

    // batch index is wave-uniform (wave's 4 pixels never straddle 65536)
    const int bb = __builtin_amdgcn_readfirstlane(p >> 16);
    const float* inb = inp + (size_t)bb * (HW * HW * CH);

    // ---- encoded coords: 3 loads, same address across 16-lane group ----
    const uint2* e = (const uint2*)(ws + (size_t)p * 12u);
    const uint2 eA = e[0];                       // taps 0..3
    const uint2 eB = e[1];                       // taps 4..7
    const unsigned eC = *(const unsigned*)(e + 2); // tap 8 (+pad)

    unsigned enc[9];
    enc[0] = eA.x & 0xffffu; enc[1] = eA.x >> 16;
    enc[2] = eA.y & 0xffffu; enc[3] = eA.y >> 16;
    enc[4] = eB.x & 0xffffu; enc[5] = eB.x >> 16;
    enc[6] = eB.y & 0xffffu; enc[7] = eB.y >> 16;
    enc[8] = eC & 0xffffu;

    int m = 0;
    int eo[9];
    #pragma unroll
    for (int k = 0; k < 9; ++k) {
        const int yy = (int)(enc[k] >> 8);
        const int xx = (int)(enc[k] & 255u);
        const bool valid = (yy >= 1) & (xx >= 1);
        m |= (int)valid << k;
        eo[k] = valid ? ((yy - 1) * HW + (xx - 1)) * CH : 0;
    }

    // ---- all 9 gathers in one batch (36 data VGPRs in flight) ----
    const int co = t * 4;
    float4 v[9];
    #pragma unroll
    for (int k = 0; k < 9; ++k)
        v[k] = *(const float4*)(inb + eo[k] + co);

    __syncthreads();                  // weights staged

    float acc = 0.f;
    #pragma unroll
    for (int k = 0; k < 9; ++k) {
        const float4 w = ((const float4*)wlds)[k * 16 + t];
        const float d = v[k].x * w.x + v[k].y * w.y + v[k].z * w.z + v[k].w * w.w;
        acc += ((m >> k) & 1) ? d : 0.f;
    }

    acc += __shfl_xor(acc, 8);
    acc += __shfl_xor(acc, 4);
    acc += __shfl_xor(acc, 2);
    acc += __shfl_xor(acc, 1);
    if (t == 0) out[p] = acc + bias[0];
}

// ===================== Fallback (round-0 verified kernel) =====================
__global__ __launch_bounds__(256, 6) void DeformFallback_kernel(
    const float* __restrict__ inp, const float* __restrict__ gt,
    const float* __restrict__ off, const float* __restrict__ ker,
    const float* __restrict__ bias, float* __restrict__ out)
{
    __shared__ float wlds[576];
    const int tid = threadIdx.x;
    if (tid < 144) ((float4*)wlds)[tid] = ((const float4*)ker)[tid];

    const int lane = tid & 63;
    const int wave = tid >> 6;
    const int q16  = lane & 48;
    const int t    = lane & 15;

    const int bid = blockIdx.x;
    const int vb  = (bid & 7) * 2048 + (bid >> 3);

    const int p = vb * 16 + wave * 4 + (q16 >> 4);
    const int b = p >> 16;
    const int i = (p >> 8) & 255;
    const int j = p & 255;
    const float* inb = inp + (long)b * (HW * HW * CH);

    int pack = 0;
    if (t < 9) {
        const int tap = t;
        const int ky = tap / 3, kx = tap - ky * 3;
        int iy = i + ky - 1, ix = j + kx - 1;
        bool interior = (iy >= 0) & (iy < HW) & (ix >= 0) & (ix < HW);
        int yi = interior ? iy : 0;
        int xi = interior ? ix : 0;
        float p_mask = (yi >= 1 && xi >= 1) ? gt[(yi - 1) * HW + (xi - 1)] : 0.f;
        float2 o2 = *(const float2*)(off + (long)p * 18 + 2 * tap);
        float yf = (float)yi, xf = (float)xi;
        float yof = fminf(fmaxf(floorf(yf + o2.x), 0.f), 257.f);
        float xof = fminf(fmaxf(floorf(xf + o2.y), 0.f), 257.f);
        int yo = (int)yof, xo = (int)xof;
        float p_mask_off = (yo >= 1 && yo <= HW && xo >= 1 && xo <= HW)
                           ? gt[(yo - 1) * HW + (xo - 1)] : 0.f;
        float diff = (p_mask != p_mask_off) ? 1.f : 0.f;
        float y = fminf(fmaxf(yf + o2.x * diff, 0.f), 255.f);
        float x = fminf(fmaxf(xf + o2.y * diff, 0.f), 255.f);
        int y0 = (int)y;
        int x0 = (int)x;
        bool valid = (y0 >= 1) & (x0 >= 1);
        int eoff = ((y0 - 1) * HW + (x0 - 1)) * CH;
        pack = valid ? eoff : -1;
    }

    int pk[9];
    #pragma unroll
    for (int k = 0; k < 9; ++k) pk[k] = __shfl(pack, q16 + k);

    float4 v[9];
    #pragma unroll
    for (int k = 0; k < 9; ++k) {
        int eo2 = pk[k] >= 0 ? pk[k] : 0;
        v[k] = *(const float4*)(inb + eo2 + t * 4);
    }

    __syncthreads();

    float acc = 0.f;
    #pragma unroll
    for (int k = 0; k < 9; ++k) {
        float s = pk[k] >= 0 ? 1.f : 0.f;
        float4 w = ((const float4*)wlds)[k * 16 + t];
        float d = v[k].x * w.x + v[k].y * w.y + v[k].z * w.z + v[k].w * w.w;
        acc = fmaf(s, d, acc);
    }

    acc += __shfl_xor(acc, 8);
    acc += __shfl_xor(acc, 4);
    acc += __shfl_xor(acc, 2);
    acc += __shfl_xor(acc, 1);
    if (t == 0) out[p] = acc + bias[0];
}

extern "C" void kernel_launch(void* const* d_in, const int* in_sizes, int n_in,
                              void* d_out, int out_size, void* d_ws, size_t ws_size,
                              hipStream_t stream) {
    const float* inp  = (const float*)d_in[0];
    const float* gt   = (const float*)d_in[1];
    const float* off  = (const float*)d_in[2];
    const float* ker  = (const float*)d_in[3];
    const float* bias = (const float*)d_in[4];
    float* out = (float*)d_out;

    if (d_ws != nullptr && ws_size >= WS_BYTES) {
        // A: 262144*9 threads / 256 = 9216 blocks (exact)
        DeformA_kernel<<<9216, 256, 0, stream>>>(gt, off, (unsigned short*)d_ws);
        // B: 262144 pixels / 16 per block = 16384 blocks
        DeformB_kernel<<<16384, 256, 0, stream>>>(
            inp, (const unsigned short*)d_ws, ker, bias, out);
    } else {
        DeformFallback_kernel<<<16384, 256, 0, stream>>>(inp, gt, off, ker, bias, out);
    }
}